// Round 11
// baseline (41.533 us; speedup 1.0000x reference)
//
#include <hip/hip_runtime.h>
#include <hip/hip_bf16.h>

// Problem constants (fixed by the reference setup)
#define Nn 2
#define Tt 8
#define Cc 3
#define Hh 128
#define Ww 128
#define Dd 64
#define NT (Nn * Tt)
#define HW (Hh * Ww)

typedef float f32x4 __attribute__((ext_vector_type(4)));

// ---------------------------------------------------------------------------
// Memset-shaped store pattern: ONE channel per thread, one contiguous
// float4 store per thread (the rocclr fill kernel that hits 6.9 TB/s writes
// exactly one stream per thread; our previous kernels wrote 3 streams at
// 4 MB spacing -- this round isolates that variable).
// Setup (rank-1 factored homography Hg = W0 - (u/dep)v^T) by thread 0 into
// LDS. Per thread: projection (6 FMA), division-free gate (true bound
// 1.0078 from the reference's [-1,1]-grid-on-pixel-coords quirk), heavy
// bilinear path (identical numerics to the passing R5/R7/R10 kernels) only
// near the valid locus, gathering just this thread's channel.
// grid = (48, Dd, NT): x = c*16 + chunk  ->  consecutive blocks write
// consecutive 64 KB within one (nt,c,d) plane. block = 256.
// ---------------------------------------------------------------------------
__global__ __launch_bounds__(256) void homog_fused(
    const float* __restrict__ images,  // (NT,C,H,W)
    const float* __restrict__ intr,    // (N,T,3,3)
    const float* __restrict__ extr,    // (N,T,4,4)
    const float* __restrict__ depths,  // (D,)
    float* __restrict__ out)           // (NT,C,D,H,W)
{
    const int d     = blockIdx.y;
    const int nt    = blockIdx.z;
    const int c     = blockIdx.x >> 4;          // channel 0..2
    const int chunk = blockIdx.x & 15;          // pixel chunk 0..15

    __shared__ float Ms[12];   // rows padded to 4

    if (threadIdx.x == 0) {
        const int n = nt >> 3;                      // Tt == 8
        const float* Kv = intr + nt * 9;
        const float* Kr = intr + (n * Tt) * 9;      // intrinsics[n,0]
        const float* Ev = extr + nt * 16;
        const float* Er = extr + (n * Tt) * 16;     // extrinsics[n,0]

        float Rr[3][3], Rv[3][3], tr[3], tv[3];
        #pragma unroll
        for (int i = 0; i < 3; ++i) {
            #pragma unroll
            for (int j = 0; j < 3; ++j) {
                Rr[i][j] = Er[i * 4 + j];
                Rv[i][j] = Ev[i * 4 + j];
            }
            tr[i] = Er[i * 4 + 3];
            tv[i] = Ev[i * 4 + 3];
        }

        float diff[3];
        #pragma unroll
        for (int i = 0; i < 3; ++i) {
            float a = Rr[0][i] * tr[0] + Rr[1][i] * tr[1] + Rr[2][i] * tr[2];
            float b = Rv[0][i] * tv[0] + Rv[1][i] * tv[1] + Rv[2][i] * tv[2];
            diff[i] = a - b;
        }
        float nr[3] = {Rr[2][0], Rr[2][1], Rr[2][2]};

        // inv(K_ref) via adjugate
        float k0 = Kr[0], k1 = Kr[1], k2 = Kr[2];
        float k3 = Kr[3], k4 = Kr[4], k5 = Kr[5];
        float k6 = Kr[6], k7 = Kr[7], k8 = Kr[8];
        float c00 = k4 * k8 - k5 * k7;
        float c01 = k5 * k6 - k3 * k8;
        float c02 = k3 * k7 - k4 * k6;
        float det = k0 * c00 + k1 * c01 + k2 * c02;
        float invd = 1.0f / det;
        float iK[3][3];
        iK[0][0] = c00 * invd;
        iK[0][1] = (k2 * k7 - k1 * k8) * invd;
        iK[0][2] = (k1 * k5 - k2 * k4) * invd;
        iK[1][0] = c01 * invd;
        iK[1][1] = (k0 * k8 - k2 * k6) * invd;
        iK[1][2] = (k2 * k3 - k0 * k5) * invd;
        iK[2][0] = c02 * invd;
        iK[2][1] = (k1 * k6 - k0 * k7) * invd;
        iK[2][2] = (k0 * k4 - k1 * k3) * invd;

        float refM[3][3], KR[3][3];
        #pragma unroll
        for (int i = 0; i < 3; ++i)
            #pragma unroll
            for (int j = 0; j < 3; ++j) {
                refM[i][j] = Rr[i][0] * iK[0][j] + Rr[i][1] * iK[1][j] + Rr[i][2] * iK[2][j];
                KR[i][j]   = Kv[i * 3 + 0] * Rv[0][j] + Kv[i * 3 + 1] * Rv[1][j] + Kv[i * 3 + 2] * Rv[2][j];
            }

        float W0[3][3], u[3], v[3];
        #pragma unroll
        for (int i = 0; i < 3; ++i) {
            #pragma unroll
            for (int j = 0; j < 3; ++j)
                W0[i][j] = KR[i][0] * refM[0][j] + KR[i][1] * refM[1][j] + KR[i][2] * refM[2][j];
            u[i] = KR[i][0] * diff[0] + KR[i][1] * diff[1] + KR[i][2] * diff[2];
            v[i] = refM[0][i] * nr[0] + refM[1][i] * nr[1] + refM[2][i] * nr[2];
        }

        const float rdep = __builtin_amdgcn_rcpf(depths[d]);
        #pragma unroll
        for (int i = 0; i < 3; ++i) {
            float ui = u[i] * rdep;
            #pragma unroll
            for (int j = 0; j < 3; ++j)
                Ms[i * 4 + j] = W0[i][j] - ui * v[j];
        }
    }
    __syncthreads();

    const f32x4 row0 = *reinterpret_cast<const f32x4*>(&Ms[0]);
    const f32x4 row1 = *reinterpret_cast<const f32x4*>(&Ms[4]);
    const f32x4 row2 = *reinterpret_cast<const f32x4*>(&Ms[8]);
    const float m0 = row0.x, m1 = row0.y, m2 = row0.z;
    const float m3 = row1.x, m4 = row1.y, m5 = row1.z;
    const float m6 = row2.x, m7 = row2.y, m8 = row2.z;

    const int p0 = (chunk * 256 + threadIdx.x) << 2;   // first pixel of quad
    const int h  = p0 >> 7;                            // Ww == 128
    const int w  = p0 & 127;

    // Reference quirk: coords = (h + 0.5, w + 0.5, 1)
    const float xc = (float)h + 0.5f;
    const float yc = (float)w + 0.5f;
    const float n0 = fmaf(m1, yc, fmaf(m0, xc, m2));
    const float n1 = fmaf(m4, yc, fmaf(m3, xc, m5));
    const float n2 = fmaf(m7, yc, fmaf(m6, xc, m8));

    float r[4] = {0.0f, 0.0f, 0.0f, 0.0f};

    // ---- quad-level interval gate (conservative; exact gate re-run inside) ----
    {
        const float e0 = fmaf(3.0f, m1, n0);
        const float e1 = fmaf(3.0f, m4, n1);
        const float e2 = fmaf(3.0f, m7, n2);
        const float T  = fmaf(1.02f, fmaxf(fabsf(n2), fabsf(e2)), 1e-6f);
        const float mn0 = (n0 * e0 > 0.0f) ? fminf(fabsf(n0), fabsf(e0)) : 0.0f;
        const float mn1 = (n1 * e1 > 0.0f) ? fminf(fabsf(n1), fabsf(e1)) : 0.0f;

        if (mn0 <= T && mn1 <= T) {
            const float* img = images + (nt * Cc + c) * HW;
            float a0 = n0, a1 = n1, a2 = n2;
            #pragma unroll
            for (int k = 0; k < 4; ++k) {
                float t = fmaf(1.02f, fabsf(a2), 1e-6f);
                if (fabsf(a0) <= t && fabsf(a1) <= t) {
                    float z  = (a2 == 0.0f) ? 1e-7f : a2;
                    float rz = __builtin_amdgcn_rcpf(z);
                    float gx = ((a0 * rz + 1.0f) * (float)Ww - 1.0f) * 0.5f;
                    float gy = ((a1 * rz + 1.0f) * (float)Hh - 1.0f) * 0.5f;

                    float x0f = floorf(gx), y0f = floorf(gy);
                    float x1f = x0f + 1.0f, y1f = y0f + 1.0f;
                    float wx1 = gx - x0f, wx0 = 1.0f - wx1;
                    float wy1 = gy - y0f, wy0 = 1.0f - wy1;

                    float v00 = (x0f >= 0.0f && x0f <= 127.0f && y0f >= 0.0f && y0f <= 127.0f) ? 1.0f : 0.0f;
                    float v10 = (x1f >= 0.0f && x1f <= 127.0f && y0f >= 0.0f && y0f <= 127.0f) ? 1.0f : 0.0f;
                    float v01 = (x0f >= 0.0f && x0f <= 127.0f && y1f >= 0.0f && y1f <= 127.0f) ? 1.0f : 0.0f;
                    float v11 = (x1f >= 0.0f && x1f <= 127.0f && y1f >= 0.0f && y1f <= 127.0f) ? 1.0f : 0.0f;

                    float w00 = (wx0 * wy0) * v00;
                    float w10 = (wx1 * wy0) * v10;
                    float w01 = (wx0 * wy1) * v01;
                    float w11 = (wx1 * wy1) * v11;

                    if (w00 != 0.0f || w10 != 0.0f || w01 != 0.0f || w11 != 0.0f) {
                        int xi0 = (int)fminf(fmaxf(x0f, 0.0f), 127.0f);
                        int xi1 = (int)fminf(fmaxf(x1f, 0.0f), 127.0f);
                        int yi0 = (int)fminf(fmaxf(y0f, 0.0f), 127.0f);
                        int yi1 = (int)fminf(fmaxf(y1f, 0.0f), 127.0f);
                        int i00 = yi0 * Ww + xi0;
                        int i10 = yi0 * Ww + xi1;
                        int i01 = yi1 * Ww + xi0;
                        int i11 = yi1 * Ww + xi1;
                        r[k] = img[i00] * w00 + img[i10] * w10 + img[i01] * w01 + img[i11] * w11;
                    }
                }
                a0 += m1; a1 += m4; a2 += m7;   // next pixel: yc += 1
            }
        }
    }

    const size_t ob = ((size_t)(nt * Cc + c) * Dd + d) * HW + p0;
    f32x4 s = {r[0], r[1], r[2], r[3]};
    *reinterpret_cast<f32x4*>(&out[ob]) = s;
}

extern "C" void kernel_launch(void* const* d_in, const int* in_sizes, int n_in,
                              void* d_out, int out_size, void* d_ws, size_t ws_size,
                              hipStream_t stream) {
    const float* images = (const float*)d_in[0];
    const float* intr   = (const float*)d_in[1];
    const float* extr   = (const float*)d_in[2];
    const float* depths = (const float*)d_in[3];
    float* out = (float*)d_out;

    homog_fused<<<dim3(48, Dd, NT), dim3(256), 0, stream>>>(
        images, intr, extr, depths, out);
}

// Round 12
// 34.532 us; speedup vs baseline: 1.2028x; 1.2028x over previous
//
#include <hip/hip_runtime.h>
#include <hip/hip_bf16.h>

// Problem constants (fixed by the reference setup)
#define Nn 2
#define Tt 8
#define Cc 3
#define Hh 128
#define Ww 128
#define Dd 64
#define NT (Nn * Tt)
#define HW (Hh * Ww)

typedef float f32x4 __attribute__((ext_vector_type(4)));

// ---------------------------------------------------------------------------
// EXACT R5 kernel body (best: 35.8 us) with ONE change: 512-thread blocks,
// halving workgroup count 65536 -> 32768 to test the command-processor
// dispatch-rate hypothesis. Per-thread setup (compiler scalarizes the
// block-uniform homography chain to SALU), rank-1 factored homography
// Hg = W0 - (u/dep)v^T, 4 px/thread, division-free gate (|n0|<=1.02|n2|+eps;
// true bound 1.0078 from the reference's [-1,1]-grid-on-pixel-coords quirk),
// heavy bilinear path only near the valid locus, plain float4 stores.
// grid = (HW/2048, D, NT), block = 512
// ---------------------------------------------------------------------------
__global__ __launch_bounds__(512) void homog_fused(
    const float* __restrict__ images,  // (NT,C,H,W)
    const float* __restrict__ intr,    // (N,T,3,3)
    const float* __restrict__ extr,    // (N,T,4,4)
    const float* __restrict__ depths,  // (D,)
    float* __restrict__ out)           // (NT,C,D,H,W)
{
    const int q  = blockIdx.x * 512 + threadIdx.x;  // quad index
    const int p0 = q << 2;
    const int h  = p0 >> 7;                         // Ww == 128
    const int w  = p0 & 127;
    const int d  = blockIdx.y;
    const int nt = blockIdx.z;
    const int n  = nt >> 3;                         // Tt == 8

    const float* Kv = intr + nt * 9;
    const float* Kr = intr + (n * Tt) * 9;          // intrinsics[n,0]
    const float* Ev = extr + nt * 16;
    const float* Er = extr + (n * Tt) * 16;         // extrinsics[n,0]

    float Rr[3][3], Rv[3][3], tr[3], tv[3];
    #pragma unroll
    for (int i = 0; i < 3; ++i) {
        #pragma unroll
        for (int j = 0; j < 3; ++j) {
            Rr[i][j] = Er[i * 4 + j];
            Rv[i][j] = Ev[i * 4 + j];
        }
        tr[i] = Er[i * 4 + 3];
        tv[i] = Ev[i * 4 + 3];
    }

    float diff[3];
    #pragma unroll
    for (int i = 0; i < 3; ++i) {
        float a = Rr[0][i] * tr[0] + Rr[1][i] * tr[1] + Rr[2][i] * tr[2];
        float b = Rv[0][i] * tv[0] + Rv[1][i] * tv[1] + Rv[2][i] * tv[2];
        diff[i] = a - b;
    }
    float nr[3] = {Rr[2][0], Rr[2][1], Rr[2][2]};

    // inv(K_ref) via adjugate
    float k0 = Kr[0], k1 = Kr[1], k2 = Kr[2];
    float k3 = Kr[3], k4 = Kr[4], k5 = Kr[5];
    float k6 = Kr[6], k7 = Kr[7], k8 = Kr[8];
    float c00 = k4 * k8 - k5 * k7;
    float c01 = k5 * k6 - k3 * k8;
    float c02 = k3 * k7 - k4 * k6;
    float det = k0 * c00 + k1 * c01 + k2 * c02;
    float invd = 1.0f / det;
    float iK[3][3];
    iK[0][0] = c00 * invd;
    iK[0][1] = (k2 * k7 - k1 * k8) * invd;
    iK[0][2] = (k1 * k5 - k2 * k4) * invd;
    iK[1][0] = c01 * invd;
    iK[1][1] = (k0 * k8 - k2 * k6) * invd;
    iK[1][2] = (k2 * k3 - k0 * k5) * invd;
    iK[2][0] = c02 * invd;
    iK[2][1] = (k1 * k6 - k0 * k7) * invd;
    iK[2][2] = (k0 * k4 - k1 * k3) * invd;

    // refM = R_ref @ inv(K_ref) ; KR = K_view @ R_view
    float refM[3][3], KR[3][3];
    #pragma unroll
    for (int i = 0; i < 3; ++i)
        #pragma unroll
        for (int j = 0; j < 3; ++j) {
            refM[i][j] = Rr[i][0] * iK[0][j] + Rr[i][1] * iK[1][j] + Rr[i][2] * iK[2][j];
            KR[i][j]   = Kv[i * 3 + 0] * Rv[0][j] + Kv[i * 3 + 1] * Rv[1][j] + Kv[i * 3 + 2] * Rv[2][j];
        }

    // W0 = KR @ refM ; u = KR @ diff ; v = refM^T @ nr
    float W0[3][3], u[3], v[3];
    #pragma unroll
    for (int i = 0; i < 3; ++i) {
        #pragma unroll
        for (int j = 0; j < 3; ++j)
            W0[i][j] = KR[i][0] * refM[0][j] + KR[i][1] * refM[1][j] + KR[i][2] * refM[2][j];
        u[i] = KR[i][0] * diff[0] + KR[i][1] * diff[1] + KR[i][2] * diff[2];
        v[i] = refM[0][i] * nr[0] + refM[1][i] * nr[1] + refM[2][i] * nr[2];
    }

    // Hg = W0 - (u/dep) v^T
    const float rdep = __builtin_amdgcn_rcpf(depths[d]);
    const float u0 = u[0] * rdep, u1 = u[1] * rdep, u2 = u[2] * rdep;
    const float m0 = W0[0][0] - u0 * v[0], m1 = W0[0][1] - u0 * v[1], m2 = W0[0][2] - u0 * v[2];
    const float m3 = W0[1][0] - u1 * v[0], m4 = W0[1][1] - u1 * v[1], m5 = W0[1][2] - u1 * v[2];
    const float m6 = W0[2][0] - u2 * v[0], m7 = W0[2][1] - u2 * v[1], m8 = W0[2][2] - u2 * v[2];

    // Reference quirk: coords = (h + 0.5, w + 0.5, 1)
    const float xc = (float)h + 0.5f;
    const float yc = (float)w + 0.5f;
    const float n0 = fmaf(m1, yc, fmaf(m0, xc, m2));
    const float n1 = fmaf(m4, yc, fmaf(m3, xc, m5));
    const float n2 = fmaf(m7, yc, fmaf(m6, xc, m8));

    float r0[4], r1[4], r2[4];
    #pragma unroll
    for (int k = 0; k < 4; ++k) { r0[k] = 0.0f; r1[k] = 0.0f; r2[k] = 0.0f; }

    // ---- cheap division-free gate over the 4 pixels ----
    bool poss[4];
    {
        float a0 = n0, a1 = n1, a2 = n2;
        #pragma unroll
        for (int k = 0; k < 4; ++k) {
            float t = fmaf(1.02f, fabsf(a2), 1e-6f);
            poss[k] = (fabsf(a0) <= t) && (fabsf(a1) <= t);
            a0 += m1; a1 += m4; a2 += m7;
        }
    }

    if (poss[0] || poss[1] || poss[2] || poss[3]) {
        const float* img = images + nt * (Cc * HW);
        float a0 = n0, a1 = n1, a2 = n2;
        #pragma unroll
        for (int k = 0; k < 4; ++k) {
            if (poss[k]) {
                float z  = (a2 == 0.0f) ? 1e-7f : a2;
                float rz = __builtin_amdgcn_rcpf(z);
                float gx = ((a0 * rz + 1.0f) * (float)Ww - 1.0f) * 0.5f;
                float gy = ((a1 * rz + 1.0f) * (float)Hh - 1.0f) * 0.5f;

                float x0f = floorf(gx), y0f = floorf(gy);
                float x1f = x0f + 1.0f, y1f = y0f + 1.0f;
                float wx1 = gx - x0f, wx0 = 1.0f - wx1;
                float wy1 = gy - y0f, wy0 = 1.0f - wy1;

                float v00 = (x0f >= 0.0f && x0f <= 127.0f && y0f >= 0.0f && y0f <= 127.0f) ? 1.0f : 0.0f;
                float v10 = (x1f >= 0.0f && x1f <= 127.0f && y0f >= 0.0f && y0f <= 127.0f) ? 1.0f : 0.0f;
                float v01 = (x0f >= 0.0f && x0f <= 127.0f && y1f >= 0.0f && y1f <= 127.0f) ? 1.0f : 0.0f;
                float v11 = (x1f >= 0.0f && x1f <= 127.0f && y1f >= 0.0f && y1f <= 127.0f) ? 1.0f : 0.0f;

                float w00 = (wx0 * wy0) * v00;
                float w10 = (wx1 * wy0) * v10;
                float w01 = (wx0 * wy1) * v01;
                float w11 = (wx1 * wy1) * v11;

                if (w00 != 0.0f || w10 != 0.0f || w01 != 0.0f || w11 != 0.0f) {
                    int xi0 = (int)fminf(fmaxf(x0f, 0.0f), 127.0f);
                    int xi1 = (int)fminf(fmaxf(x1f, 0.0f), 127.0f);
                    int yi0 = (int)fminf(fmaxf(y0f, 0.0f), 127.0f);
                    int yi1 = (int)fminf(fmaxf(y1f, 0.0f), 127.0f);
                    int i00 = yi0 * Ww + xi0;
                    int i10 = yi0 * Ww + xi1;
                    int i01 = yi1 * Ww + xi0;
                    int i11 = yi1 * Ww + xi1;
                    r0[k] = img[i00] * w00 + img[i10] * w10 + img[i01] * w01 + img[i11] * w11;
                    r1[k] = img[HW + i00] * w00 + img[HW + i10] * w10 + img[HW + i01] * w01 + img[HW + i11] * w11;
                    r2[k] = img[2 * HW + i00] * w00 + img[2 * HW + i10] * w10 + img[2 * HW + i01] * w01 + img[2 * HW + i11] * w11;
                }
            }
            a0 += m1; a1 += m4; a2 += m7;   // next pixel: yc += 1
        }
    }

    size_t obase = ((size_t)(nt * Cc) * Dd + d) * HW + p0;
    f32x4 s0 = {r0[0], r0[1], r0[2], r0[3]};
    f32x4 s1 = {r1[0], r1[1], r1[2], r1[3]};
    f32x4 s2 = {r2[0], r2[1], r2[2], r2[3]};
    *reinterpret_cast<f32x4*>(&out[obase])                       = s0;
    *reinterpret_cast<f32x4*>(&out[obase + (size_t)Dd * HW])     = s1;
    *reinterpret_cast<f32x4*>(&out[obase + (size_t)2 * Dd * HW]) = s2;
}

extern "C" void kernel_launch(void* const* d_in, const int* in_sizes, int n_in,
                              void* d_out, int out_size, void* d_ws, size_t ws_size,
                              hipStream_t stream) {
    const float* images = (const float*)d_in[0];
    const float* intr   = (const float*)d_in[1];
    const float* extr   = (const float*)d_in[2];
    const float* depths = (const float*)d_in[3];
    float* out = (float*)d_out;

    homog_fused<<<dim3(HW / 2048, Dd, NT), dim3(512), 0, stream>>>(
        images, intr, extr, depths, out);
}

// Round 13
// 34.282 us; speedup vs baseline: 1.2115x; 1.0073x over previous
//
#include <hip/hip_runtime.h>
#include <hip/hip_bf16.h>

// Problem constants (fixed by the reference setup)
#define Nn 2
#define Tt 8
#define Cc 3
#define Hh 128
#define Ww 128
#define Dd 64
#define NT (Nn * Tt)
#define HW (Hh * Ww)

typedef float f32x4 __attribute__((ext_vector_type(4)));

// ---------------------------------------------------------------------------
// EXACT R12 kernel body (best: 34.5 us) with ONE change: 1024-thread blocks,
// halving workgroup count 32768 -> 16384 (command-processor dispatch-rate
// axis, which R12 showed is a real contributor: 65k->32k WGs = -1.3 us).
// Per-thread setup (block-uniform, compiler scalarizes), rank-1 factored
// homography Hg = W0 - (u/dep)v^T, 4 px/thread, division-free gate
// (|n0|<=1.02|n2|+eps; true bound 1.0078 from the reference's
// [-1,1]-grid-on-pixel-coords quirk), heavy bilinear path only near the
// valid locus, plain float4 stores.
// grid = (HW/4096, D, NT), block = 1024
// ---------------------------------------------------------------------------
__global__ __launch_bounds__(1024) void homog_fused(
    const float* __restrict__ images,  // (NT,C,H,W)
    const float* __restrict__ intr,    // (N,T,3,3)
    const float* __restrict__ extr,    // (N,T,4,4)
    const float* __restrict__ depths,  // (D,)
    float* __restrict__ out)           // (NT,C,D,H,W)
{
    const int q  = blockIdx.x * 1024 + threadIdx.x; // quad index
    const int p0 = q << 2;
    const int h  = p0 >> 7;                         // Ww == 128
    const int w  = p0 & 127;
    const int d  = blockIdx.y;
    const int nt = blockIdx.z;
    const int n  = nt >> 3;                         // Tt == 8

    const float* Kv = intr + nt * 9;
    const float* Kr = intr + (n * Tt) * 9;          // intrinsics[n,0]
    const float* Ev = extr + nt * 16;
    const float* Er = extr + (n * Tt) * 16;         // extrinsics[n,0]

    float Rr[3][3], Rv[3][3], tr[3], tv[3];
    #pragma unroll
    for (int i = 0; i < 3; ++i) {
        #pragma unroll
        for (int j = 0; j < 3; ++j) {
            Rr[i][j] = Er[i * 4 + j];
            Rv[i][j] = Ev[i * 4 + j];
        }
        tr[i] = Er[i * 4 + 3];
        tv[i] = Ev[i * 4 + 3];
    }

    float diff[3];
    #pragma unroll
    for (int i = 0; i < 3; ++i) {
        float a = Rr[0][i] * tr[0] + Rr[1][i] * tr[1] + Rr[2][i] * tr[2];
        float b = Rv[0][i] * tv[0] + Rv[1][i] * tv[1] + Rv[2][i] * tv[2];
        diff[i] = a - b;
    }
    float nr[3] = {Rr[2][0], Rr[2][1], Rr[2][2]};

    // inv(K_ref) via adjugate
    float k0 = Kr[0], k1 = Kr[1], k2 = Kr[2];
    float k3 = Kr[3], k4 = Kr[4], k5 = Kr[5];
    float k6 = Kr[6], k7 = Kr[7], k8 = Kr[8];
    float c00 = k4 * k8 - k5 * k7;
    float c01 = k5 * k6 - k3 * k8;
    float c02 = k3 * k7 - k4 * k6;
    float det = k0 * c00 + k1 * c01 + k2 * c02;
    float invd = 1.0f / det;
    float iK[3][3];
    iK[0][0] = c00 * invd;
    iK[0][1] = (k2 * k7 - k1 * k8) * invd;
    iK[0][2] = (k1 * k5 - k2 * k4) * invd;
    iK[1][0] = c01 * invd;
    iK[1][1] = (k0 * k8 - k2 * k6) * invd;
    iK[1][2] = (k2 * k3 - k0 * k5) * invd;
    iK[2][0] = c02 * invd;
    iK[2][1] = (k1 * k6 - k0 * k7) * invd;
    iK[2][2] = (k0 * k4 - k1 * k3) * invd;

    // refM = R_ref @ inv(K_ref) ; KR = K_view @ R_view
    float refM[3][3], KR[3][3];
    #pragma unroll
    for (int i = 0; i < 3; ++i)
        #pragma unroll
        for (int j = 0; j < 3; ++j) {
            refM[i][j] = Rr[i][0] * iK[0][j] + Rr[i][1] * iK[1][j] + Rr[i][2] * iK[2][j];
            KR[i][j]   = Kv[i * 3 + 0] * Rv[0][j] + Kv[i * 3 + 1] * Rv[1][j] + Kv[i * 3 + 2] * Rv[2][j];
        }

    // W0 = KR @ refM ; u = KR @ diff ; v = refM^T @ nr
    float W0[3][3], u[3], v[3];
    #pragma unroll
    for (int i = 0; i < 3; ++i) {
        #pragma unroll
        for (int j = 0; j < 3; ++j)
            W0[i][j] = KR[i][0] * refM[0][j] + KR[i][1] * refM[1][j] + KR[i][2] * refM[2][j];
        u[i] = KR[i][0] * diff[0] + KR[i][1] * diff[1] + KR[i][2] * diff[2];
        v[i] = refM[0][i] * nr[0] + refM[1][i] * nr[1] + refM[2][i] * nr[2];
    }

    // Hg = W0 - (u/dep) v^T
    const float rdep = __builtin_amdgcn_rcpf(depths[d]);
    const float u0 = u[0] * rdep, u1 = u[1] * rdep, u2 = u[2] * rdep;
    const float m0 = W0[0][0] - u0 * v[0], m1 = W0[0][1] - u0 * v[1], m2 = W0[0][2] - u0 * v[2];
    const float m3 = W0[1][0] - u1 * v[0], m4 = W0[1][1] - u1 * v[1], m5 = W0[1][2] - u1 * v[2];
    const float m6 = W0[2][0] - u2 * v[0], m7 = W0[2][1] - u2 * v[1], m8 = W0[2][2] - u2 * v[2];

    // Reference quirk: coords = (h + 0.5, w + 0.5, 1)
    const float xc = (float)h + 0.5f;
    const float yc = (float)w + 0.5f;
    const float n0 = fmaf(m1, yc, fmaf(m0, xc, m2));
    const float n1 = fmaf(m4, yc, fmaf(m3, xc, m5));
    const float n2 = fmaf(m7, yc, fmaf(m6, xc, m8));

    float r0[4], r1[4], r2[4];
    #pragma unroll
    for (int k = 0; k < 4; ++k) { r0[k] = 0.0f; r1[k] = 0.0f; r2[k] = 0.0f; }

    // ---- cheap division-free gate over the 4 pixels ----
    bool poss[4];
    {
        float a0 = n0, a1 = n1, a2 = n2;
        #pragma unroll
        for (int k = 0; k < 4; ++k) {
            float t = fmaf(1.02f, fabsf(a2), 1e-6f);
            poss[k] = (fabsf(a0) <= t) && (fabsf(a1) <= t);
            a0 += m1; a1 += m4; a2 += m7;
        }
    }

    if (poss[0] || poss[1] || poss[2] || poss[3]) {
        const float* img = images + nt * (Cc * HW);
        float a0 = n0, a1 = n1, a2 = n2;
        #pragma unroll
        for (int k = 0; k < 4; ++k) {
            if (poss[k]) {
                float z  = (a2 == 0.0f) ? 1e-7f : a2;
                float rz = __builtin_amdgcn_rcpf(z);
                float gx = ((a0 * rz + 1.0f) * (float)Ww - 1.0f) * 0.5f;
                float gy = ((a1 * rz + 1.0f) * (float)Hh - 1.0f) * 0.5f;

                float x0f = floorf(gx), y0f = floorf(gy);
                float x1f = x0f + 1.0f, y1f = y0f + 1.0f;
                float wx1 = gx - x0f, wx0 = 1.0f - wx1;
                float wy1 = gy - y0f, wy0 = 1.0f - wy1;

                float v00 = (x0f >= 0.0f && x0f <= 127.0f && y0f >= 0.0f && y0f <= 127.0f) ? 1.0f : 0.0f;
                float v10 = (x1f >= 0.0f && x1f <= 127.0f && y0f >= 0.0f && y0f <= 127.0f) ? 1.0f : 0.0f;
                float v01 = (x0f >= 0.0f && x0f <= 127.0f && y1f >= 0.0f && y1f <= 127.0f) ? 1.0f : 0.0f;
                float v11 = (x1f >= 0.0f && x1f <= 127.0f && y1f >= 0.0f && y1f <= 127.0f) ? 1.0f : 0.0f;

                float w00 = (wx0 * wy0) * v00;
                float w10 = (wx1 * wy0) * v10;
                float w01 = (wx0 * wy1) * v01;
                float w11 = (wx1 * wy1) * v11;

                if (w00 != 0.0f || w10 != 0.0f || w01 != 0.0f || w11 != 0.0f) {
                    int xi0 = (int)fminf(fmaxf(x0f, 0.0f), 127.0f);
                    int xi1 = (int)fminf(fmaxf(x1f, 0.0f), 127.0f);
                    int yi0 = (int)fminf(fmaxf(y0f, 0.0f), 127.0f);
                    int yi1 = (int)fminf(fmaxf(y1f, 0.0f), 127.0f);
                    int i00 = yi0 * Ww + xi0;
                    int i10 = yi0 * Ww + xi1;
                    int i01 = yi1 * Ww + xi0;
                    int i11 = yi1 * Ww + xi1;
                    r0[k] = img[i00] * w00 + img[i10] * w10 + img[i01] * w01 + img[i11] * w11;
                    r1[k] = img[HW + i00] * w00 + img[HW + i10] * w10 + img[HW + i01] * w01 + img[HW + i11] * w11;
                    r2[k] = img[2 * HW + i00] * w00 + img[2 * HW + i10] * w10 + img[2 * HW + i01] * w01 + img[2 * HW + i11] * w11;
                }
            }
            a0 += m1; a1 += m4; a2 += m7;   // next pixel: yc += 1
        }
    }

    size_t obase = ((size_t)(nt * Cc) * Dd + d) * HW + p0;
    f32x4 s0 = {r0[0], r0[1], r0[2], r0[3]};
    f32x4 s1 = {r1[0], r1[1], r1[2], r1[3]};
    f32x4 s2 = {r2[0], r2[1], r2[2], r2[3]};
    *reinterpret_cast<f32x4*>(&out[obase])                       = s0;
    *reinterpret_cast<f32x4*>(&out[obase + (size_t)Dd * HW])     = s1;
    *reinterpret_cast<f32x4*>(&out[obase + (size_t)2 * Dd * HW]) = s2;
}

extern "C" void kernel_launch(void* const* d_in, const int* in_sizes, int n_in,
                              void* d_out, int out_size, void* d_ws, size_t ws_size,
                              hipStream_t stream) {
    const float* images = (const float*)d_in[0];
    const float* intr   = (const float*)d_in[1];
    const float* extr   = (const float*)d_in[2];
    const float* depths = (const float*)d_in[3];
    float* out = (float*)d_out;

    homog_fused<<<dim3(HW / 4096, Dd, NT), dim3(1024), 0, stream>>>(
        images, intr, extr, depths, out);
}